// Round 13
// baseline (455.387 us; speedup 1.0000x reference)
//
#include <hip/hip_runtime.h>
#include <hip/hip_cooperative_groups.h>
#include <math.h>

namespace cg = cooperative_groups;

// SatLossEvaluator R13 — single cooperative kernel fusing R10's pipeline:
// phase 0 zero counters | phase A multisplit binning (+vpdl build) |
// phase B bucket accum (float N + u64 D|T) + fused loss | phase C reduce.
// R12 post-mortem: binary search was latency-hidden (VALU 22->5.6% but time
// rose); TILE=8192 40KB-LDS bin is the local optimum -> reverted. Remaining
// lever: ~100us of inter-dispatch overhead -> fuse via grid.sync().
//
// record u32 = (f_local:11 << 20) | (ef_sign:1 << 19) | (var_idx:19)
// bucket = fun_idx >> 11 (S_FUN=2048, K<=1024)
// ws: [gcounts K u32][partials K double][vpdl V float2][records K*cap u32]

#define THREADS 256
#define S_LOG2  11
#define S_FUN   2048
#define K_MAX   1024
#define TILE    8192
#define ITEMS   (TILE / THREADS)   // 32 records per thread
#define QUADS   (ITEMS / 4)
#define DSCALE  1024.0f
#define DRECIP  (1.0f / 1024.0f)
#define TSCALE  65536.0f
#define TRECIP  (1.0f / 65536.0f)

typedef unsigned uint4n __attribute__((ext_vector_type(4)));
typedef float    float4n __attribute__((ext_vector_type(4)));
typedef float    float2n __attribute__((ext_vector_type(2)));

__global__ void __launch_bounds__(THREADS, 4)
fused_all(const int* __restrict__ gmap, const float* __restrict__ ef,
          const float* __restrict__ vp, const float* __restrict__ dl,
          float2n* __restrict__ vpdl, unsigned* __restrict__ gcounts,
          unsigned* __restrict__ records, double* __restrict__ partials,
          float* __restrict__ out,
          const float* __restrict__ gs, const float* __restrict__ mc,
          const float* __restrict__ eps_p, const int* __restrict__ ls_p,
          int E, int V, int F, int K, int cap, int tiles, int fblocks) {
    cg::grid_group grid = cg::this_grid();
    // 40960B phase-union -> 4 blocks/CU
    __shared__ __attribute__((aligned(16))) unsigned char smem[40960];
    unsigned* hist    = (unsigned*)smem;            // 4KB
    unsigned* offs    = hist + K_MAX;               // 4KB
    unsigned* staging = offs + K_MAX;               // 32KB (scan scratch too)
    unsigned long long* accDT = (unsigned long long*)smem;       // 16KB
    float* accN = (float*)(smem + 16384);                        // 8KB
    float* red  = (float*)(smem + 16384 + 8192);
    double* smd = (double*)smem;                                 // phase C

    // ---- phase 0: zero global counters (ws is 0xAA-poisoned) ----
    for (int i = blockIdx.x * THREADS + threadIdx.x; i < K;
         i += gridDim.x * THREADS)
        gcounts[i] = 0u;
    grid.sync();

    // ---- phase A: binning tiles + vpdl table build (grid-stride) ----
    for (int vt = blockIdx.x; vt < tiles + fblocks; vt += gridDim.x) {
        if (vt >= tiles) {
            int q = (vt - tiles) * THREADS + threadIdx.x;   // 4 elems/thread
            if (q * 4 + 3 < V) {
                float4n p4 = __builtin_nontemporal_load((const float4n*)vp + q);
                float4n d4 = __builtin_nontemporal_load((const float4n*)dl + q);
                #pragma unroll
                for (int c = 0; c < 4; ++c) {
                    float2n t; t.x = p4[c]; t.y = d4[c];
                    __builtin_nontemporal_store(t, vpdl + q * 4 + c);
                }
            } else {
                for (int c = 0; c < 4; ++c) {
                    int i = q * 4 + c;
                    if (i < V) { float2n t; t.x = vp[i]; t.y = dl[i]; vpdl[i] = t; }
                }
            }
            continue;
        }

        unsigned rec[ITEMS];
        unsigned bp[ITEMS];   // (bucket:10 << 13) | pos:13

        int base = vt * TILE;
        int n = min(TILE, E - base);
        bool full = (n == TILE);

        for (int i = threadIdx.x; i < K; i += THREADS) hist[i] = 0u;
        __syncthreads();

        const unsigned* funp = (const unsigned*)(gmap + E) + base;
        const unsigned* varp = (const unsigned*)gmap + base;
        const float*    efp  = ef + base;

        #pragma unroll
        for (int k = 0; k < QUADS; ++k) {
            int q = k * THREADS + threadIdx.x;
            if (full || q * 4 + 3 < n) {
                uint4n  f4 = __builtin_nontemporal_load((const uint4n*)funp + q);
                uint4n  v4 = __builtin_nontemporal_load((const uint4n*)varp + q);
                float4n e4 = __builtin_nontemporal_load((const float4n*)efp + q);
                #pragma unroll
                for (int c = 0; c < 4; ++c) {
                    unsigned f = f4[c], v = v4[c];
                    float    e = e4[c];
                    unsigned b = f >> S_LOG2;
                    rec[k * 4 + c] = ((f & (S_FUN - 1)) << 20) |
                                     ((e < 0.0f ? 1u : 0u) << 19) | v;
                    unsigned pos = atomicAdd(&hist[b], 1u);
                    bp[k * 4 + c] = (b << 13) | pos;
                }
            } else {
                #pragma unroll
                for (int c = 0; c < 4; ++c) {
                    int j = q * 4 + c;
                    if (j < n) {
                        unsigned f = funp[j], v = varp[j];
                        float    e = efp[j];
                        unsigned b = f >> S_LOG2;
                        rec[k * 4 + c] = ((f & (S_FUN - 1)) << 20) |
                                         ((e < 0.0f ? 1u : 0u) << 19) | v;
                        unsigned pos = atomicAdd(&hist[b], 1u);
                        bp[k * 4 + c] = (b << 13) | pos;
                    } else bp[k * 4 + c] = 0xFFFFFFFFu;
                }
            }
        }
        __syncthreads();

        // exclusive scan hist -> offs (scratch aliased into staging)
        {
            unsigned* wred = staging;
            int t4 = threadIdx.x * 4;
            unsigned a0 = (t4 + 0 < K) ? hist[t4 + 0] : 0u;
            unsigned a1 = (t4 + 1 < K) ? hist[t4 + 1] : 0u;
            unsigned a2 = (t4 + 2 < K) ? hist[t4 + 2] : 0u;
            unsigned a3 = (t4 + 3 < K) ? hist[t4 + 3] : 0u;
            unsigned s = a0 + a1 + a2 + a3;
            unsigned sc = s;
            int lane = threadIdx.x & 63, wid = threadIdx.x >> 6;
            #pragma unroll
            for (int d = 1; d < 64; d <<= 1) {
                unsigned t = __shfl_up(sc, d, 64);
                if (lane >= d) sc += t;
            }
            if (lane == 63) wred[wid] = sc;
            __syncthreads();
            unsigned wb = 0;
            for (int w = 0; w < wid; ++w) wb += wred[w];
            unsigned ex = wb + sc - s;
            if (t4 + 0 < K) { offs[t4 + 0] = ex; ex += a0; }
            if (t4 + 1 < K) { offs[t4 + 1] = ex; ex += a1; }
            if (t4 + 2 < K) { offs[t4 + 2] = ex; ex += a2; }
            if (t4 + 3 < K) { offs[t4 + 3] = ex; ex += a3; }
        }
        __syncthreads();

        // reserve runs; hist[b] := gbase - offs delta
        for (int b = threadIdx.x; b < K; b += THREADS) {
            unsigned h = hist[b];
            if (h) hist[b] = atomicAdd(&gcounts[b], h) - offs[b];
        }
        __syncthreads();

        // scatter bucket-contiguously
        #pragma unroll
        for (int k = 0; k < ITEMS; ++k) {
            unsigned m = bp[k];
            if (m != 0xFFFFFFFFu)
                staging[offs[m >> 13] + (m & 0x1FFFu)] = rec[k];
        }
        __syncthreads();

        // copy out (binary search; latency-hidden — R12 proved it's free)
        for (int j = threadIdx.x; j < n; j += THREADS) {
            unsigned r = staging[j];
            int lo = 0, hi = K - 1;
            while (lo < hi) {
                int mid = (lo + hi + 1) >> 1;
                if (offs[mid] <= (unsigned)j) lo = mid; else hi = mid - 1;
            }
            unsigned dst = hist[lo] + (unsigned)j;
            if (dst < (unsigned)cap)
                __builtin_nontemporal_store(r, &records[(size_t)lo * cap + dst]);
        }
        __syncthreads();   // protect smem before next iteration
    }
    grid.sync();

    // ---- phase B: bucket accumulation + fused loss ----
    float coeff = fminf(sqrtf(gs[0]), mc[0]);   // ALPHA = 0.5
    float epsv = eps_p[0];
    int   ls   = ls_p[0];
    for (int b = blockIdx.x; b < K; b += gridDim.x) {
        for (int i = threadIdx.x; i < S_FUN; i += THREADS) {
            accN[i] = 0.0f; accDT[i] = 0ull;
        }
        __syncthreads();

        unsigned cnt = gcounts[b];
        if (cnt > (unsigned)cap) cnt = (unsigned)cap;
        const unsigned* rec = records + (size_t)b * cap;

        #define PROC1(R_, T_) {                                            \
            float e_ = ((R_) >> 19) & 1u ? -1.0f : 1.0f;                   \
            unsigned s_ = (R_) >> 20;                                      \
            float ev_ = e_ * (T_).x + (1.0f - e_) * 0.5f;                  \
            float w_ = __expf(coeff * ev_);                                \
            unsigned dq_ = (unsigned)(w_ * DSCALE + 0.5f);                 \
            int tq_ = (int)rintf(e_ * (T_).y * TSCALE);                    \
            atomicAdd(&accN[s_], w_ * ev_);                                \
            atomicAdd(&accDT[s_],                                          \
                ((unsigned long long)(long long)tq_ << 32) + dq_); }

        unsigned n4 = cnt >> 2;
        for (unsigned j = threadIdx.x; j < n4; j += 2 * THREADS) {
            unsigned j2 = j + THREADS;
            uint4n ra = __builtin_nontemporal_load((const uint4n*)rec + j);
            if (j2 < n4) {
                uint4n rb = __builtin_nontemporal_load((const uint4n*)rec + j2);
                unsigned r[8] = {ra[0], ra[1], ra[2], ra[3],
                                 rb[0], rb[1], rb[2], rb[3]};
                float2n t[8];
                #pragma unroll
                for (int c = 0; c < 8; ++c) t[c] = vpdl[r[c] & 0x7FFFFu];
                #pragma unroll
                for (int c = 0; c < 8; ++c) PROC1(r[c], t[c]);
            } else {
                unsigned r[4] = {ra[0], ra[1], ra[2], ra[3]};
                float2n t[4];
                #pragma unroll
                for (int c = 0; c < 4; ++c) t[c] = vpdl[r[c] & 0x7FFFFu];
                #pragma unroll
                for (int c = 0; c < 4; ++c) PROC1(r[c], t[c]);
            }
        }
        for (unsigned j = (n4 << 2) + threadIdx.x; j < cnt; j += THREADS) {
            unsigned r = rec[j];
            float2n t = vpdl[r & 0x7FFFFu];
            PROC1(r, t);
        }
        #undef PROC1
        __syncthreads();

        float local = 0.0f;
        int fbase = b << S_LOG2;
        for (int i = threadIdx.x; i < S_FUN; i += THREADS) {
            int fg = fbase + i;
            if (fg < F) {
                unsigned long long nd = accDT[i];
                float D = (float)(unsigned)(nd & 0xFFFFFFFFull) * DRECIP;
                float T = (float)(int)(nd >> 32) * TRECIP;
                float cv = D / fmaxf(accN[i], epsv);
                float d = cv - 1.0f;
                float p = 1.0f;
                for (int k = 0; k < ls; ++k) p *= d;   // handles d<0 (ls odd)
                cv = T * (1.0f + p);
                local += __logf(fmaxf(cv, epsv));
            }
        }
        #pragma unroll
        for (int off = 32; off > 0; off >>= 1)
            local += __shfl_down(local, off, 64);
        int lane = threadIdx.x & 63, wid = threadIdx.x >> 6;
        if (lane == 0) red[wid] = local;
        __syncthreads();
        if (threadIdx.x == 0) {
            float s = 0.0f;
            #pragma unroll
            for (int w = 0; w < THREADS / 64; ++w) s += red[w];
            partials[b] = (double)s;
        }
        __syncthreads();   // protect smem before next bucket
    }
    grid.sync();

    // ---- phase C: final mean (block 0) ----
    if (blockIdx.x == 0) {
        double local = 0.0;
        for (int i = threadIdx.x; i < K; i += THREADS) local += partials[i];
        smd[threadIdx.x] = local;
        __syncthreads();
        for (int s = THREADS / 2; s > 0; s >>= 1) {
            if ((int)threadIdx.x < s) smd[threadIdx.x] += smd[threadIdx.x + s];
            __syncthreads();
        }
        if (threadIdx.x == 0) out[0] = (float)(smd[0] / (double)F);
    }
}

extern "C" void kernel_launch(void* const* d_in, const int* in_sizes, int n_in,
                              void* d_out, int out_size, void* d_ws, size_t ws_size,
                              hipStream_t stream) {
    const float* vp   = (const float*)d_in[0];
    const float* dl   = (const float*)d_in[1];
    const int*   gmap = (const int*)d_in[3];
    const float* ef   = (const float*)d_in[6];
    const float* gs   = (const float*)d_in[8];
    const float* eps  = (const float*)d_in[9];
    const float* mc   = (const float*)d_in[10];
    const int*   ls   = (const int*)d_in[11];

    int V = in_sizes[0];
    int F = in_sizes[5];
    int E = in_sizes[6];
    int K = (F + S_FUN - 1) / S_FUN;   // 977 at F=2M

    size_t off = ((size_t)K * sizeof(unsigned) + 15) & ~(size_t)15;
    unsigned* gcounts = (unsigned*)d_ws;
    double* partials = (double*)((char*)d_ws + off);
    off = (off + (size_t)K * sizeof(double) + 15) & ~(size_t)15;
    float2n* vpdl = (float2n*)((char*)d_ws + off);
    off = (off + (size_t)V * sizeof(float2n) + 15) & ~(size_t)15;

    long long cap64 = (ws_size > off)
        ? (long long)((ws_size - off) / ((size_t)K * sizeof(unsigned))) : 4;
    if (cap64 > 16384) cap64 = 16384;   // mean E/K ~8.2K, sigma ~90
    cap64 &= ~3LL;
    if (cap64 < 4) cap64 = 4;
    int cap = (int)cap64;

    unsigned* records = (unsigned*)((char*)d_ws + off);
    float* out = (float*)d_out;

    int tiles = (E + TILE - 1) / TILE;
    int fblocks = (V + THREADS * 4 - 1) / (THREADS * 4);

    // co-residency-safe grid (LDS 40960 -> 4/CU; launch_bounds caps VGPR<=128)
    int per_cu = 0;
    hipOccupancyMaxActiveBlocksPerMultiprocessor(&per_cu, fused_all, THREADS, 0);
    if (per_cu < 1) per_cu = 1;
    int grid = per_cu * 256;
    if (grid > 1024) grid = 1024;   // K_MAX buckets; >4/CU adds nothing

    void* args[] = {
        (void*)&gmap, (void*)&ef, (void*)&vp, (void*)&dl, (void*)&vpdl,
        (void*)&gcounts, (void*)&records, (void*)&partials, (void*)&out,
        (void*)&gs, (void*)&mc, (void*)&eps, (void*)&ls,
        (void*)&E, (void*)&V, (void*)&F, (void*)&K, (void*)&cap,
        (void*)&tiles, (void*)&fblocks
    };
    hipLaunchCooperativeKernel(reinterpret_cast<void*>(fused_all),
                               dim3(grid), dim3(THREADS), args, 0, stream);
}

// Round 14
// 285.427 us; speedup vs baseline: 1.5955x; 1.5955x over previous
//
#include <hip/hip_runtime.h>
#include <math.h>

// SatLossEvaluator R14 — R10 pipeline (best measured: 278us) with
// final_reduce folded into bucket_accum via last-block-done + device-scope
// f64 atomic sum (cross-XCD safe: all communication through atomic RMWs at
// the coherence point, no plain-store/fence handoff).
// R13 post-mortem: cooperative fusion regressed 278->455 (static grid-stride
// imbalance: 442 blocks ran 2 serial bin tiles; grid.sync tail serialization).
//
// record u32 = (f_local:11 << 20) | (ef_sign:1 << 19) | (var_idx:19)
// bucket = fun_idx >> 11 (S_FUN=2048, K<=1024)
// ws: [gcounts K u32][done u32][gsum double][vpdl V float2][records K*cap u32]

#define THREADS 256
#define S_LOG2  11
#define S_FUN   2048
#define K_MAX   1024
#define TILE    8192
#define ITEMS   (TILE / THREADS)   // 32 records per thread
#define QUADS   (ITEMS / 4)
#define DSCALE  1024.0f
#define DRECIP  (1.0f / 1024.0f)
#define TSCALE  65536.0f
#define TRECIP  (1.0f / 65536.0f)

typedef unsigned uint4n __attribute__((ext_vector_type(4)));
typedef float    float4n __attribute__((ext_vector_type(4)));
typedef float    float2n __attribute__((ext_vector_type(2)));

__global__ void __launch_bounds__(THREADS)
bin_edges(const int* __restrict__ gmap,      // [2,E]
          const float* __restrict__ ef,
          const float* __restrict__ vp,
          const float* __restrict__ dl,
          float2n* __restrict__ vpdl,
          unsigned* __restrict__ gcounts,    // K
          unsigned* __restrict__ records,    // K * cap
          int E, int V, int K, int cap, int tiles) {
    // LDS = 4KB + 4KB + 32KB = 40960 B exactly -> 4 blocks/CU
    __shared__ unsigned hist[K_MAX];   // counts -> (gbase - offs) delta
    __shared__ unsigned offs[K_MAX];   // exclusive scan
    __shared__ unsigned staging[TILE]; // first words double as scan scratch

    if (blockIdx.x >= (unsigned)tiles) {
        // ---- fused table build: vpdl[i] = (vp[i], dl[i]) ----
        int q = (blockIdx.x - tiles) * THREADS + threadIdx.x;
        if (q * 4 + 3 < V) {
            float4n p4 = __builtin_nontemporal_load((const float4n*)vp + q);
            float4n d4 = __builtin_nontemporal_load((const float4n*)dl + q);
            #pragma unroll
            for (int c = 0; c < 4; ++c) {
                float2n t; t.x = p4[c]; t.y = d4[c];
                __builtin_nontemporal_store(t, vpdl + q * 4 + c);
            }
        } else {
            for (int c = 0; c < 4; ++c) {
                int i = q * 4 + c;
                if (i < V) { float2n t; t.x = vp[i]; t.y = dl[i]; vpdl[i] = t; }
            }
        }
        return;
    }

    unsigned rec[ITEMS];
    unsigned bp[ITEMS];   // (bucket:10 << 13) | pos:13 ; 0xFFFFFFFF = invalid

    int base = blockIdx.x * TILE;
    int n = min(TILE, E - base);
    bool full = (n == TILE);

    for (int i = threadIdx.x; i < K; i += THREADS) hist[i] = 0u;
    __syncthreads();

    const unsigned* funp = (const unsigned*)(gmap + E) + base;
    const unsigned* varp = (const unsigned*)gmap + base;
    const float*    efp  = ef + base;

    #pragma unroll
    for (int k = 0; k < QUADS; ++k) {
        int q = k * THREADS + threadIdx.x;
        if (full || q * 4 + 3 < n) {
            uint4n  f4 = __builtin_nontemporal_load((const uint4n*)funp + q);
            uint4n  v4 = __builtin_nontemporal_load((const uint4n*)varp + q);
            float4n e4 = __builtin_nontemporal_load((const float4n*)efp + q);
            #pragma unroll
            for (int c = 0; c < 4; ++c) {
                unsigned f = f4[c], v = v4[c];
                float    e = e4[c];
                unsigned b = f >> S_LOG2;
                rec[k * 4 + c] = ((f & (S_FUN - 1)) << 20) |
                                 ((e < 0.0f ? 1u : 0u) << 19) | v;
                unsigned pos = atomicAdd(&hist[b], 1u);
                bp[k * 4 + c] = (b << 13) | pos;
            }
        } else {
            #pragma unroll
            for (int c = 0; c < 4; ++c) {
                int j = q * 4 + c;
                if (j < n) {
                    unsigned f = funp[j], v = varp[j];
                    float    e = efp[j];
                    unsigned b = f >> S_LOG2;
                    rec[k * 4 + c] = ((f & (S_FUN - 1)) << 20) |
                                     ((e < 0.0f ? 1u : 0u) << 19) | v;
                    unsigned pos = atomicAdd(&hist[b], 1u);
                    bp[k * 4 + c] = (b << 13) | pos;
                } else bp[k * 4 + c] = 0xFFFFFFFFu;
            }
        }
    }
    __syncthreads();

    // exclusive scan hist -> offs (wred scratch aliased into staging)
    {
        unsigned* wred = staging;
        int t4 = threadIdx.x * 4;
        unsigned a0 = (t4 + 0 < K) ? hist[t4 + 0] : 0u;
        unsigned a1 = (t4 + 1 < K) ? hist[t4 + 1] : 0u;
        unsigned a2 = (t4 + 2 < K) ? hist[t4 + 2] : 0u;
        unsigned a3 = (t4 + 3 < K) ? hist[t4 + 3] : 0u;
        unsigned s = a0 + a1 + a2 + a3;
        unsigned sc = s;
        int lane = threadIdx.x & 63, wid = threadIdx.x >> 6;
        #pragma unroll
        for (int d = 1; d < 64; d <<= 1) {
            unsigned t = __shfl_up(sc, d, 64);
            if (lane >= d) sc += t;
        }
        if (lane == 63) wred[wid] = sc;
        __syncthreads();
        unsigned wb = 0;
        for (int w = 0; w < wid; ++w) wb += wred[w];
        unsigned ex = wb + sc - s;
        if (t4 + 0 < K) { offs[t4 + 0] = ex; ex += a0; }
        if (t4 + 1 < K) { offs[t4 + 1] = ex; ex += a1; }
        if (t4 + 2 < K) { offs[t4 + 2] = ex; ex += a2; }
        if (t4 + 3 < K) { offs[t4 + 3] = ex; ex += a3; }
    }
    __syncthreads();

    // reserve global runs; overwrite hist in place with (gbase - offs) delta
    for (int b = threadIdx.x; b < K; b += THREADS) {
        unsigned h = hist[b];
        if (h) hist[b] = atomicAdd(&gcounts[b], h) - offs[b];
    }
    __syncthreads();

    // scatter records bucket-contiguously into staging
    #pragma unroll
    for (int k = 0; k < ITEMS; ++k) {
        unsigned m = bp[k];
        if (m != 0xFFFFFFFFu)
            staging[offs[m >> 13] + (m & 0x1FFFu)] = rec[k];
    }
    __syncthreads();

    // copy out: dst = delta[lo] + j ; bucket lo via binary search on offs
    // (search is latency-hidden — R12 measured its removal as a regression)
    for (int j = threadIdx.x; j < n; j += THREADS) {
        unsigned r = staging[j];
        int lo = 0, hi = K - 1;
        while (lo < hi) {
            int mid = (lo + hi + 1) >> 1;
            if (offs[mid] <= (unsigned)j) lo = mid; else hi = mid - 1;
        }
        unsigned dst = hist[lo] + (unsigned)j;   // gbase - offs + j
        if (dst < (unsigned)cap)                 // drop-guard (never hit)
            __builtin_nontemporal_store(r, &records[(size_t)lo * cap + dst]);
    }
}

// bucket_accum: R10 scheme (float N + u64-packed D|T) + fused loss epilogue
// + last-block-done final reduction (device-scope f64 atomic sum).
__global__ void __launch_bounds__(THREADS)
bucket_accum(const float2n* __restrict__ vpdl,
             const unsigned* __restrict__ gcounts,
             const unsigned* __restrict__ records,
             const float* __restrict__ gs,
             const float* __restrict__ mc,
             const float* __restrict__ eps_p,
             const int* __restrict__ ls_p,
             unsigned* __restrict__ done,   // zeroed by memset
             double* __restrict__ gsum,     // zeroed by memset
             float* __restrict__ out,
             int F, int cap) {
    __shared__ float accN[S_FUN];                // exact float: eps-sensitive
    __shared__ unsigned long long accDT[S_FUN];  // lo: D*2^10, hi: T*2^16 signed
    __shared__ float red[THREADS / 64];
    __shared__ unsigned is_last;

    int b = blockIdx.x;
    for (int i = threadIdx.x; i < S_FUN; i += THREADS) {
        accN[i] = 0.0f; accDT[i] = 0ull;
    }
    __syncthreads();

    float coeff = fminf(sqrtf(gs[0]), mc[0]);   // ALPHA = 0.5
    unsigned cnt = gcounts[b];
    if (cnt > (unsigned)cap) cnt = (unsigned)cap;
    const unsigned* rec = records + (size_t)b * cap;

    #define PROC1(R_, T_) {                                            \
        float e_ = ((R_) >> 19) & 1u ? -1.0f : 1.0f;                   \
        unsigned s_ = (R_) >> 20;                                      \
        float ev_ = e_ * (T_).x + (1.0f - e_) * 0.5f;                  \
        float w_ = __expf(coeff * ev_);                                \
        unsigned dq_ = (unsigned)(w_ * DSCALE + 0.5f);                 \
        int tq_ = (int)rintf(e_ * (T_).y * TSCALE);                    \
        atomicAdd(&accN[s_], w_ * ev_);                                \
        atomicAdd(&accDT[s_],                                          \
            ((unsigned long long)(long long)tq_ << 32) + dq_); }

    unsigned n4 = cnt >> 2;
    for (unsigned j = threadIdx.x; j < n4; j += 2 * THREADS) {
        unsigned j2 = j + THREADS;
        uint4n ra = __builtin_nontemporal_load((const uint4n*)rec + j);
        if (j2 < n4) {
            uint4n rb = __builtin_nontemporal_load((const uint4n*)rec + j2);
            unsigned r[8] = {ra[0], ra[1], ra[2], ra[3], rb[0], rb[1], rb[2], rb[3]};
            float2n t[8];
            #pragma unroll
            for (int c = 0; c < 8; ++c) t[c] = vpdl[r[c] & 0x7FFFFu];
            #pragma unroll
            for (int c = 0; c < 8; ++c) PROC1(r[c], t[c]);
        } else {
            unsigned r[4] = {ra[0], ra[1], ra[2], ra[3]};
            float2n t[4];
            #pragma unroll
            for (int c = 0; c < 4; ++c) t[c] = vpdl[r[c] & 0x7FFFFu];
            #pragma unroll
            for (int c = 0; c < 4; ++c) PROC1(r[c], t[c]);
        }
    }
    for (unsigned j = (n4 << 2) + threadIdx.x; j < cnt; j += THREADS) {
        unsigned r = rec[j];
        float2n t = vpdl[r & 0x7FFFFu];
        PROC1(r, t);
    }
    #undef PROC1
    __syncthreads();

    // fused epilogue: decode D/T, exact N, per-function loss, block reduce
    float epsv = eps_p[0];
    int   ls   = ls_p[0];
    float local = 0.0f;
    int fbase = b << S_LOG2;
    for (int i = threadIdx.x; i < S_FUN; i += THREADS) {
        int fg = fbase + i;
        if (fg < F) {
            unsigned long long nd = accDT[i];
            float D = (float)(unsigned)(nd & 0xFFFFFFFFull) * DRECIP;
            float T = (float)(int)(nd >> 32) * TRECIP;
            float cv = D / fmaxf(accN[i], epsv);
            float d = cv - 1.0f;
            float p = 1.0f;
            for (int k = 0; k < ls; ++k) p *= d;   // handles d<0 (ls odd)
            cv = T * (1.0f + p);
            local += __logf(fmaxf(cv, epsv));
        }
    }
    #pragma unroll
    for (int off = 32; off > 0; off >>= 1)
        local += __shfl_down(local, off, 64);
    int lane = threadIdx.x & 63, wid = threadIdx.x >> 6;
    if (lane == 0) red[wid] = local;
    __syncthreads();

    // last-block-done: block sum -> device-scope f64 atomic; final block
    // reads the total back through the same coherence point and writes out.
    if (threadIdx.x == 0) {
        float s = 0.0f;
        #pragma unroll
        for (int w = 0; w < THREADS / 64; ++w) s += red[w];
        atomicAdd(gsum, (double)s);
        unsigned old = atomicAdd(done, 1u);
        is_last = (old == (unsigned)gridDim.x - 1u);
        if (is_last) {
            double total = atomicAdd(gsum, 0.0);   // coherent read
            out[0] = (float)(total / (double)F);
        }
    }
}

extern "C" void kernel_launch(void* const* d_in, const int* in_sizes, int n_in,
                              void* d_out, int out_size, void* d_ws, size_t ws_size,
                              hipStream_t stream) {
    const float* vp   = (const float*)d_in[0];
    const float* dl   = (const float*)d_in[1];
    const int*   gmap = (const int*)d_in[3];
    const float* ef   = (const float*)d_in[6];
    const float* gs   = (const float*)d_in[8];
    const float* eps  = (const float*)d_in[9];
    const float* mc   = (const float*)d_in[10];
    const int*   ls   = (const int*)d_in[11];

    const int V = in_sizes[0];
    const int F = in_sizes[5];
    const int E = in_sizes[6];
    const int K = (F + S_FUN - 1) / S_FUN;   // 977 at F=2M

    // header: [gcounts K u32][done u32][pad->8][gsum double]
    size_t done_off = (size_t)K * sizeof(unsigned);
    size_t gsum_off = (done_off + sizeof(unsigned) + 7) & ~(size_t)7;
    size_t hdr = (gsum_off + sizeof(double) + 15) & ~(size_t)15;

    unsigned* gcounts = (unsigned*)d_ws;
    unsigned* done    = (unsigned*)((char*)d_ws + done_off);
    double*   gsum    = (double*)((char*)d_ws + gsum_off);

    size_t off = hdr;
    float2n* vpdl = (float2n*)((char*)d_ws + off);
    off = (off + (size_t)V * sizeof(float2n) + 15) & ~(size_t)15;

    long long cap = (ws_size > off)
        ? (long long)((ws_size - off) / ((size_t)K * sizeof(unsigned))) : 4;
    if (cap > 16384) cap = 16384;   // mean E/K ~8.2K, sigma ~90
    cap &= ~3LL;
    if (cap < 4) cap = 4;

    unsigned* records = (unsigned*)((char*)d_ws + off);

    hipMemsetAsync(d_ws, 0, hdr, stream);   // zeroes gcounts + done + gsum

    int tiles = (E + TILE - 1) / TILE;
    int fblocks = (V + THREADS * 4 - 1) / (THREADS * 4);
    bin_edges<<<tiles + fblocks, THREADS, 0, stream>>>(
        gmap, ef, vp, dl, vpdl, gcounts, records, E, V, K, (int)cap, tiles);

    bucket_accum<<<K, THREADS, 0, stream>>>(vpdl, gcounts, records,
                                            gs, mc, eps, ls,
                                            done, gsum, (float*)d_out,
                                            F, (int)cap);
}

// Round 15
// 277.322 us; speedup vs baseline: 1.6421x; 1.0292x over previous
//
#include <hip/hip_runtime.h>
#include <math.h>

// SatLossEvaluator FINAL (= R10, best measured: 278us) — multisplit binning
// (40KB LDS, 4 blocks/CU, fused vpdl table build) + bucket accumulation
// (exact float N + u64-packed D:2^10|T:2^16 LDS atomics, fused loss epilogue)
// + final reduce.
//
// Floor accounting (R1-R14):
//  - bin_edges ~103us: latency floor — occupancy (R10), search removal (R12),
//    direct writes (R4) all nulled. Streams 96MB + 8M LDS pos-atomics.
//  - bucket_accum ~70us: LDS-RMW slot floor (~24M bank-slots x ~3.5cyc) —
//    nontemporal (R7), occupancy (R5), packing (R9), restructure (R11) probed.
//  - ~100us fixed harness cost: fusion (R13) regressed, dispatch-fold (R14)
//    neutral.
//
// record u32 = (f_local:11 << 20) | (ef_sign:1 << 19) | (var_idx:19)
// bucket = fun_idx >> 11 (S_FUN=2048, K<=1024)
// ws: [gcounts K u32][partials K double][vpdl V float2][records K*cap u32]

#define THREADS 256
#define S_LOG2  11
#define S_FUN   2048
#define K_MAX   1024
#define TILE    8192
#define ITEMS   (TILE / THREADS)   // 32 records per thread
#define QUADS   (ITEMS / 4)
#define DSCALE  1024.0f
#define DRECIP  (1.0f / 1024.0f)
#define TSCALE  65536.0f
#define TRECIP  (1.0f / 65536.0f)

typedef unsigned uint4n __attribute__((ext_vector_type(4)));
typedef float    float4n __attribute__((ext_vector_type(4)));
typedef float    float2n __attribute__((ext_vector_type(2)));

__global__ void __launch_bounds__(THREADS)
bin_edges(const int* __restrict__ gmap,      // [2,E]
          const float* __restrict__ ef,
          const float* __restrict__ vp,
          const float* __restrict__ dl,
          float2n* __restrict__ vpdl,
          unsigned* __restrict__ gcounts,    // K
          unsigned* __restrict__ records,    // K * cap
          int E, int V, int K, int cap, int tiles) {
    // LDS = 4KB + 4KB + 32KB = 40960 B exactly -> 4 blocks/CU
    __shared__ unsigned hist[K_MAX];   // counts -> (gbase - offs) delta
    __shared__ unsigned offs[K_MAX];   // exclusive scan
    __shared__ unsigned staging[TILE]; // first words double as scan scratch

    if (blockIdx.x >= (unsigned)tiles) {
        // ---- fused table build: vpdl[i] = (vp[i], dl[i]) ----
        int q = (blockIdx.x - tiles) * THREADS + threadIdx.x;
        if (q * 4 + 3 < V) {
            float4n p4 = __builtin_nontemporal_load((const float4n*)vp + q);
            float4n d4 = __builtin_nontemporal_load((const float4n*)dl + q);
            #pragma unroll
            for (int c = 0; c < 4; ++c) {
                float2n t; t.x = p4[c]; t.y = d4[c];
                __builtin_nontemporal_store(t, vpdl + q * 4 + c);
            }
        } else {
            for (int c = 0; c < 4; ++c) {
                int i = q * 4 + c;
                if (i < V) { float2n t; t.x = vp[i]; t.y = dl[i]; vpdl[i] = t; }
            }
        }
        return;
    }

    unsigned rec[ITEMS];
    unsigned bp[ITEMS];   // (bucket:10 << 13) | pos:13 ; 0xFFFFFFFF = invalid

    int base = blockIdx.x * TILE;
    int n = min(TILE, E - base);
    bool full = (n == TILE);

    for (int i = threadIdx.x; i < K; i += THREADS) hist[i] = 0u;
    __syncthreads();

    const unsigned* funp = (const unsigned*)(gmap + E) + base;
    const unsigned* varp = (const unsigned*)gmap + base;
    const float*    efp  = ef + base;

    #pragma unroll
    for (int k = 0; k < QUADS; ++k) {
        int q = k * THREADS + threadIdx.x;
        if (full || q * 4 + 3 < n) {
            uint4n  f4 = __builtin_nontemporal_load((const uint4n*)funp + q);
            uint4n  v4 = __builtin_nontemporal_load((const uint4n*)varp + q);
            float4n e4 = __builtin_nontemporal_load((const float4n*)efp + q);
            #pragma unroll
            for (int c = 0; c < 4; ++c) {
                unsigned f = f4[c], v = v4[c];
                float    e = e4[c];
                unsigned b = f >> S_LOG2;
                rec[k * 4 + c] = ((f & (S_FUN - 1)) << 20) |
                                 ((e < 0.0f ? 1u : 0u) << 19) | v;
                unsigned pos = atomicAdd(&hist[b], 1u);
                bp[k * 4 + c] = (b << 13) | pos;
            }
        } else {
            #pragma unroll
            for (int c = 0; c < 4; ++c) {
                int j = q * 4 + c;
                if (j < n) {
                    unsigned f = funp[j], v = varp[j];
                    float    e = efp[j];
                    unsigned b = f >> S_LOG2;
                    rec[k * 4 + c] = ((f & (S_FUN - 1)) << 20) |
                                     ((e < 0.0f ? 1u : 0u) << 19) | v;
                    unsigned pos = atomicAdd(&hist[b], 1u);
                    bp[k * 4 + c] = (b << 13) | pos;
                } else bp[k * 4 + c] = 0xFFFFFFFFu;
            }
        }
    }
    __syncthreads();

    // exclusive scan hist -> offs (wred scratch aliased into staging)
    {
        unsigned* wred = staging;
        int t4 = threadIdx.x * 4;
        unsigned a0 = (t4 + 0 < K) ? hist[t4 + 0] : 0u;
        unsigned a1 = (t4 + 1 < K) ? hist[t4 + 1] : 0u;
        unsigned a2 = (t4 + 2 < K) ? hist[t4 + 2] : 0u;
        unsigned a3 = (t4 + 3 < K) ? hist[t4 + 3] : 0u;
        unsigned s = a0 + a1 + a2 + a3;
        unsigned sc = s;
        int lane = threadIdx.x & 63, wid = threadIdx.x >> 6;
        #pragma unroll
        for (int d = 1; d < 64; d <<= 1) {
            unsigned t = __shfl_up(sc, d, 64);
            if (lane >= d) sc += t;
        }
        if (lane == 63) wred[wid] = sc;
        __syncthreads();
        unsigned wb = 0;
        for (int w = 0; w < wid; ++w) wb += wred[w];
        unsigned ex = wb + sc - s;
        if (t4 + 0 < K) { offs[t4 + 0] = ex; ex += a0; }
        if (t4 + 1 < K) { offs[t4 + 1] = ex; ex += a1; }
        if (t4 + 2 < K) { offs[t4 + 2] = ex; ex += a2; }
        if (t4 + 3 < K) { offs[t4 + 3] = ex; ex += a3; }
    }
    __syncthreads();

    // reserve global runs; overwrite hist in place with (gbase - offs) delta
    for (int b = threadIdx.x; b < K; b += THREADS) {
        unsigned h = hist[b];
        if (h) hist[b] = atomicAdd(&gcounts[b], h) - offs[b];
    }
    __syncthreads();

    // scatter records bucket-contiguously into staging
    #pragma unroll
    for (int k = 0; k < ITEMS; ++k) {
        unsigned m = bp[k];
        if (m != 0xFFFFFFFFu)
            staging[offs[m >> 13] + (m & 0x1FFFu)] = rec[k];
    }
    __syncthreads();

    // copy out: dst = delta[lo] + j ; bucket lo via binary search on offs
    // (search is latency-hidden — R12 measured its removal as a regression)
    for (int j = threadIdx.x; j < n; j += THREADS) {
        unsigned r = staging[j];
        int lo = 0, hi = K - 1;
        while (lo < hi) {
            int mid = (lo + hi + 1) >> 1;
            if (offs[mid] <= (unsigned)j) lo = mid; else hi = mid - 1;
        }
        unsigned dst = hist[lo] + (unsigned)j;   // gbase - offs + j
        if (dst < (unsigned)cap)                 // drop-guard (never hit)
            __builtin_nontemporal_store(r, &records[(size_t)lo * cap + dst]);
    }
}

__global__ void __launch_bounds__(THREADS)
bucket_accum(const float2n* __restrict__ vpdl,
             const unsigned* __restrict__ gcounts,
             const unsigned* __restrict__ records,
             const float* __restrict__ gs,
             const float* __restrict__ mc,
             const float* __restrict__ eps_p,
             const int* __restrict__ ls_p,
             double* __restrict__ partials,
             int F, int cap) {
    __shared__ float accN[S_FUN];                // exact float: eps-sensitive
    __shared__ unsigned long long accDT[S_FUN];  // lo: D*2^10, hi: T*2^16 signed
    __shared__ float red[THREADS / 64];

    int b = blockIdx.x;
    for (int i = threadIdx.x; i < S_FUN; i += THREADS) {
        accN[i] = 0.0f; accDT[i] = 0ull;
    }
    __syncthreads();

    float coeff = fminf(sqrtf(gs[0]), mc[0]);   // ALPHA = 0.5
    unsigned cnt = gcounts[b];
    if (cnt > (unsigned)cap) cnt = (unsigned)cap;
    const unsigned* rec = records + (size_t)b * cap;

    #define PROC1(R_, T_) {                                            \
        float e_ = ((R_) >> 19) & 1u ? -1.0f : 1.0f;                   \
        unsigned s_ = (R_) >> 20;                                      \
        float ev_ = e_ * (T_).x + (1.0f - e_) * 0.5f;                  \
        float w_ = __expf(coeff * ev_);                                \
        unsigned dq_ = (unsigned)(w_ * DSCALE + 0.5f);                 \
        int tq_ = (int)rintf(e_ * (T_).y * TSCALE);                    \
        atomicAdd(&accN[s_], w_ * ev_);                                \
        atomicAdd(&accDT[s_],                                          \
            ((unsigned long long)(long long)tq_ << 32) + dq_); }

    unsigned n4 = cnt >> 2;
    // 8 records per thread per iteration: 2 vec4 loads, 8 batched gathers
    for (unsigned j = threadIdx.x; j < n4; j += 2 * THREADS) {
        unsigned j2 = j + THREADS;
        uint4n ra = __builtin_nontemporal_load((const uint4n*)rec + j);
        if (j2 < n4) {
            uint4n rb = __builtin_nontemporal_load((const uint4n*)rec + j2);
            unsigned r[8] = {ra[0], ra[1], ra[2], ra[3], rb[0], rb[1], rb[2], rb[3]};
            float2n t[8];
            #pragma unroll
            for (int c = 0; c < 8; ++c) t[c] = vpdl[r[c] & 0x7FFFFu];
            #pragma unroll
            for (int c = 0; c < 8; ++c) PROC1(r[c], t[c]);
        } else {
            unsigned r[4] = {ra[0], ra[1], ra[2], ra[3]};
            float2n t[4];
            #pragma unroll
            for (int c = 0; c < 4; ++c) t[c] = vpdl[r[c] & 0x7FFFFu];
            #pragma unroll
            for (int c = 0; c < 4; ++c) PROC1(r[c], t[c]);
        }
    }
    for (unsigned j = (n4 << 2) + threadIdx.x; j < cnt; j += THREADS) {
        unsigned r = rec[j];
        float2n t = vpdl[r & 0x7FFFFu];
        PROC1(r, t);
    }
    #undef PROC1
    __syncthreads();

    // fused epilogue: decode D/T, exact N, per-function loss, block reduce
    float epsv = eps_p[0];
    int   ls   = ls_p[0];
    float local = 0.0f;
    int fbase = b << S_LOG2;
    for (int i = threadIdx.x; i < S_FUN; i += THREADS) {
        int fg = fbase + i;
        if (fg < F) {
            unsigned long long nd = accDT[i];
            float D = (float)(unsigned)(nd & 0xFFFFFFFFull) * DRECIP;
            float T = (float)(int)(nd >> 32) * TRECIP;
            float cv = D / fmaxf(accN[i], epsv);
            float d = cv - 1.0f;
            float p = 1.0f;
            for (int k = 0; k < ls; ++k) p *= d;   // handles d<0 (ls odd)
            cv = T * (1.0f + p);
            local += __logf(fmaxf(cv, epsv));
        }
    }
    #pragma unroll
    for (int off = 32; off > 0; off >>= 1)
        local += __shfl_down(local, off, 64);
    int lane = threadIdx.x & 63, wid = threadIdx.x >> 6;
    if (lane == 0) red[wid] = local;
    __syncthreads();
    if (threadIdx.x == 0) {
        float s = 0.0f;
        #pragma unroll
        for (int w = 0; w < THREADS / 64; ++w) s += red[w];
        partials[b] = (double)s;
    }
}

__global__ void final_reduce(const double* __restrict__ partials, int nparts,
                             float* __restrict__ out, int F) {
    __shared__ double sm[THREADS];
    double local = 0.0;
    for (int i = threadIdx.x; i < nparts; i += blockDim.x) local += partials[i];
    sm[threadIdx.x] = local;
    __syncthreads();
    for (int s = blockDim.x / 2; s > 0; s >>= 1) {
        if ((int)threadIdx.x < s) sm[threadIdx.x] += sm[threadIdx.x + s];
        __syncthreads();
    }
    if (threadIdx.x == 0) out[0] = (float)(sm[0] / (double)F);
}

extern "C" void kernel_launch(void* const* d_in, const int* in_sizes, int n_in,
                              void* d_out, int out_size, void* d_ws, size_t ws_size,
                              hipStream_t stream) {
    const float* vp   = (const float*)d_in[0];
    const float* dl   = (const float*)d_in[1];
    const int*   gmap = (const int*)d_in[3];
    const float* ef   = (const float*)d_in[6];
    const float* gs   = (const float*)d_in[8];
    const float* eps  = (const float*)d_in[9];
    const float* mc   = (const float*)d_in[10];
    const int*   ls   = (const int*)d_in[11];

    const int V = in_sizes[0];
    const int F = in_sizes[5];
    const int E = in_sizes[6];
    const int K = (F + S_FUN - 1) / S_FUN;   // 977 at F=2M

    size_t off = ((size_t)K * sizeof(unsigned) + 15) & ~(size_t)15;
    unsigned* gcounts = (unsigned*)d_ws;
    double* partials = (double*)((char*)d_ws + off);
    off = (off + (size_t)K * sizeof(double) + 15) & ~(size_t)15;
    float2n* vpdl = (float2n*)((char*)d_ws + off);
    off = (off + (size_t)V * sizeof(float2n) + 15) & ~(size_t)15;

    long long cap = (ws_size > off)
        ? (long long)((ws_size - off) / ((size_t)K * sizeof(unsigned))) : 4;
    if (cap > 16384) cap = 16384;   // mean E/K ~8.2K, sigma ~90
    cap &= ~3LL;
    if (cap < 4) cap = 4;

    unsigned* records = (unsigned*)((char*)d_ws + off);

    hipMemsetAsync(gcounts, 0, (size_t)K * sizeof(unsigned), stream);

    int tiles = (E + TILE - 1) / TILE;
    int fblocks = (V + THREADS * 4 - 1) / (THREADS * 4);
    bin_edges<<<tiles + fblocks, THREADS, 0, stream>>>(
        gmap, ef, vp, dl, vpdl, gcounts, records, E, V, K, (int)cap, tiles);

    bucket_accum<<<K, THREADS, 0, stream>>>(vpdl, gcounts, records,
                                            gs, mc, eps, ls, partials,
                                            F, (int)cap);

    final_reduce<<<1, THREADS, 0, stream>>>(partials, K, (float*)d_out, F);
}